// Round 1
// baseline (705.911 us; speedup 1.0000x reference)
//
#include <hip/hip_runtime.h>
#include <hip/hip_bf16.h>

// Problem constants
#define T_DIM 64
#define B_DIM 512
#define D_DIM 1536
#define H_DIM 1024
#define M_DIM (T_DIM * B_DIM)   // 32768 rows through the MLP
#define DISCOUNT 0.997f
#define LAM 0.95f

// GEMM tiling: 256x256 C-tile, 512 threads (8 waves, 2m x 4n), BK=64.
// Double-buffered LDS (128 KB) -> 1 block/CU; in-block 4-phase pipeline
// (T3+T4) replaces cross-block TLP. Grid = 128*4 = 512 = exactly 2 rounds
// of 256 CUs (zero tail).
#define BM 256
#define BN 256
#define BK 64
#define TILES_M (M_DIM / BM)    // 128
#define TILES_N (H_DIM / BN)    // 4
#define N_XCD 8

typedef __bf16 bf16x8 __attribute__((ext_vector_type(8)));
typedef float  f32x4  __attribute__((ext_vector_type(4)));

__device__ __forceinline__ void async_load16(const void* g, void* l) {
    __builtin_amdgcn_global_load_lds(
        (const __attribute__((address_space(1))) void*)g,
        (__attribute__((address_space(3))) void*)l,
        16, 0, 0);
}

__device__ __forceinline__ unsigned short f2bf_raw(float f) {
    __hip_bfloat16 h = __float2bfloat16(f);
    return *reinterpret_cast<unsigned short*>(&h);
}

// ---------------------------------------------------------------------------
// feat fp32 -> bf16, vectorized (float4 in, ushort4 out)
// ---------------------------------------------------------------------------
__global__ __launch_bounds__(256) void cvt_bf16_kernel(
    const float* __restrict__ x, __hip_bfloat16* __restrict__ y, long n4) {
    long i = (long)blockIdx.x * blockDim.x + threadIdx.x;
    if (i >= n4) return;
    float4 v = reinterpret_cast<const float4*>(x)[i];
    ushort4 o;
    o.x = f2bf_raw(v.x);
    o.y = f2bf_raw(v.y);
    o.z = f2bf_raw(v.z);
    o.w = f2bf_raw(v.w);
    reinterpret_cast<ushort4*>(y)[i] = o;
}

// ---------------------------------------------------------------------------
// All 4 weight transposes in one launch. W (K x N fp32) -> Wt (N x K bf16).
// ---------------------------------------------------------------------------
__global__ __launch_bounds__(256) void transpose_cvt_all_kernel(
    const float* __restrict__ W0, const float* __restrict__ W1,
    const float* __restrict__ W2, const float* __restrict__ W3,
    __hip_bfloat16* __restrict__ T0, __hip_bfloat16* __restrict__ T1,
    __hip_bfloat16* __restrict__ T2, __hip_bfloat16* __restrict__ T3) {
    __shared__ float tile[32][33];
    int z = blockIdx.z;
    const float* W;
    __hip_bfloat16* Tt;
    int K;
    if (z == 0)      { W = W0; Tt = T0; K = D_DIM; }
    else if (z == 1) { W = W1; Tt = T1; K = H_DIM; }
    else if (z == 2) { W = W2; Tt = T2; K = H_DIM; }
    else             { W = W3; Tt = T3; K = H_DIM; }
    int k0 = blockIdx.x * 32, n0 = blockIdx.y * 32;
    if (k0 >= K) return;
    int tx = threadIdx.x, ty = threadIdx.y;  // 32 x 8
    #pragma unroll
    for (int r = ty; r < 32; r += 8)
        tile[r][tx] = W[(size_t)(k0 + r) * H_DIM + n0 + tx];
    __syncthreads();
    #pragma unroll
    for (int r = ty; r < 32; r += 8)
        Tt[(size_t)(n0 + r) * K + k0 + tx] = __float2bfloat16(tile[tx][r]);
}

// ---------------------------------------------------------------------------
// C[m][n] = silu( sum_k A[m][k] * Bt[n][k] + bias[n] ), output bf16.
//
// 256x256 tile, 512 threads (8 waves = 2m x 4n), wave tile 128x64.
// Double-buffered LDS K-tiles (BK=64): A 2x32KB + B 2x32KB = 128 KB.
// Main loop = 4 phases per K-tile (quadrants of the wave tile); each phase:
//   stage 1 half-tile of K-tile t+1 (2 x global_load_lds)   [issue early]
//   ds_read fragments for this quadrant
//   s_barrier (raw, NO vmcnt drain)
//   setprio(1); 16 MFMA; setprio(0)
//   s_barrier
// Single s_waitcnt vmcnt(0) per K-tile at end of phase 3 — issued loads have
// had ~3 phases of MFMA to land. No __syncthreads() in the loop (its implicit
// vmcnt(0)-before-barrier drain was the old structure's stall).
//
// Quadrant order (mq,nq) = (0,0),(1,0),(1,1),(0,1): A frags reloaded twice,
// B frags once -> 12/8/4/8 ds_read_b128 per phase.
//
// LDS swizzle via permuted global source column (conflict-free, measured
// SQ_LDS_BANK_CONFLICT = 0 with this scheme in the previous structure):
//   LDS[row][c8] = global[row][c8 ^ (row&7)]  (c8 = 8-elem col group)
// XCD swizzle: 512 blocks, xcd = l%8; each XCD gets 16 consecutive M-panels
// x 4 N-tiles; Wt N-slices stay L2-resident. nwg%8==0 -> bijective.
// ---------------------------------------------------------------------------
__global__ __launch_bounds__(512, 2) void gemm_silu_kernel(
    const __hip_bfloat16* __restrict__ A,
    const __hip_bfloat16* __restrict__ Bt,
    const float* __restrict__ bias,
    __hip_bfloat16* __restrict__ C,
    int K) {

    __shared__ alignas(16) __hip_bfloat16 lds[65536];   // 128 KB

    __hip_bfloat16* const A0 = lds;
    __hip_bfloat16* const A1 = lds + 16384;
    __hip_bfloat16* const B0 = lds + 32768;
    __hip_bfloat16* const B1 = lds + 49152;

    const int tid  = threadIdx.x;
    const int wave = tid >> 6;         // 0..7
    const int lane = tid & 63;
    const int sub  = lane >> 3;        // staging row within 8-row chunk
    const int quad = lane >> 4;        // 0..3
    const int r16  = lane & 15;        // 0..15
    const int wm   = wave & 1;         // wave row in 2x4
    const int wn   = wave >> 1;        // wave col in 2x4 (0..3)

    // XCD-aware tile assignment: 512 blocks = 128 M-tiles x 4 N-tiles
    const int l     = blockIdx.x;
    const int xcd   = l & (N_XCD - 1);
    const int local = l >> 3;                  // 0..63
    const int tn    = local & (TILES_N - 1);   // 0..3
    const int tm    = (xcd << 4) | (local >> 2);  // 0..127
    const int m0 = tm * BM;
    const int n0 = tn * BN;

    // swizzled global column for this lane's staging load
    const int scol = ((lane & 7) ^ sub) << 3;

    // staging bases: chunk(p,i) = rows p*128 + (wave*2+i)*8 (+sub)
    const __hip_bfloat16* aBase = A  + (size_t)(m0 + wave * 16 + sub) * K + scol;
    const __hip_bfloat16* bBase = Bt + (size_t)(n0 + wave * 16 + sub) * K + scol;

    f32x4 acc[8][4];
    #pragma unroll
    for (int i = 0; i < 8; ++i)
        #pragma unroll
        for (int j = 0; j < 4; ++j)
            acc[i][j] = (f32x4){0.f, 0.f, 0.f, 0.f};

    // prologue: stage K-tile 0 into buf0 (8 loads/thread), full drain
    #pragma unroll
    for (int p = 0; p < 2; ++p)
        #pragma unroll
        for (int i = 0; i < 2; ++i) {
            async_load16(aBase + (size_t)(p * 128 + i * 8) * K,
                         A0 + (p * 16 + wave * 2 + i) * 512);
            async_load16(bBase + (size_t)(p * 128 + i * 8) * K,
                         B0 + (p * 16 + wave * 2 + i) * 512);
        }
    __syncthreads();

#define STAGE_A(p) do { \
        async_load16(aBase + (size_t)((p) * 128    ) * K + kofs, \
                     An + ((p) * 16 + wave * 2    ) * 512); \
        async_load16(aBase + (size_t)((p) * 128 + 8) * K + kofs, \
                     An + ((p) * 16 + wave * 2 + 1) * 512); \
    } while (0)
#define STAGE_B(p) do { \
        async_load16(bBase + (size_t)((p) * 128    ) * K + kofs, \
                     Bn + ((p) * 16 + wave * 2    ) * 512); \
        async_load16(bBase + (size_t)((p) * 128 + 8) * K + kofs, \
                     Bn + ((p) * 16 + wave * 2 + 1) * 512); \
    } while (0)
#define READ_A(mq) do { \
        _Pragma("unroll") \
        for (int ii = 0; ii < 4; ++ii) { \
            const int m_l = wm * 128 + ((mq) * 4 + ii) * 16 + r16; \
            _Pragma("unroll") \
            for (int ks = 0; ks < 2; ++ks) \
                af[ii][ks] = *reinterpret_cast<const bf16x8*>( \
                    &Ac[m_l * BK + (((ks * 4 + quad) ^ (m_l & 7)) << 3)]); \
        } \
    } while (0)
#define READ_B(nq) do { \
        _Pragma("unroll") \
        for (int jj = 0; jj < 2; ++jj) { \
            const int n_l = wn * 64 + ((nq) * 2 + jj) * 16 + r16; \
            _Pragma("unroll") \
            for (int ks = 0; ks < 2; ++ks) \
                bfr[jj][ks] = *reinterpret_cast<const bf16x8*>( \
                    &Bc[n_l * BK + (((ks * 4 + quad) ^ (n_l & 7)) << 3)]); \
        } \
    } while (0)
#define CLUSTER(mq, nq) do { \
        __builtin_amdgcn_s_setprio(1); \
        _Pragma("unroll") \
        for (int ii = 0; ii < 4; ++ii) \
            _Pragma("unroll") \
            for (int jj = 0; jj < 2; ++jj) { \
                acc[(mq)*4+ii][(nq)*2+jj] = __builtin_amdgcn_mfma_f32_16x16x32_bf16( \
                    af[ii][0], bfr[jj][0], acc[(mq)*4+ii][(nq)*2+jj], 0, 0, 0); \
                acc[(mq)*4+ii][(nq)*2+jj] = __builtin_amdgcn_mfma_f32_16x16x32_bf16( \
                    af[ii][1], bfr[jj][1], acc[(mq)*4+ii][(nq)*2+jj], 0, 0, 0); \
            } \
        __builtin_amdgcn_s_setprio(0); \
    } while (0)
#define BAR() __builtin_amdgcn_s_barrier()

    const int NT = K / BK;
    for (int t = 0; t < NT; ++t) {
        const bool last = (t == NT - 1);
        const __hip_bfloat16* Ac = (t & 1) ? A1 : A0;
        const __hip_bfloat16* Bc = (t & 1) ? B1 : B0;
        __hip_bfloat16* An = (t & 1) ? A0 : A1;
        __hip_bfloat16* Bn = (t & 1) ? B0 : B1;
        const size_t kofs = (size_t)(t + 1) * BK;

        bf16x8 af[4][2], bfr[2][2];

        // ---- phase 0: quadrant (0,0); stage A half 0 of tile t+1
        if (!last) STAGE_A(0);
        READ_B(0);
        READ_A(0);
        BAR();
        CLUSTER(0, 0);
        BAR();

        // ---- phase 1: quadrant (1,0); stage A half 1
        if (!last) STAGE_A(1);
        READ_A(1);
        BAR();
        CLUSTER(1, 0);
        BAR();

        // ---- phase 2: quadrant (1,1); stage B half 0 (A mq=1 reused)
        if (!last) STAGE_B(0);
        READ_B(1);
        BAR();
        CLUSTER(1, 1);
        BAR();

        // ---- phase 3: quadrant (0,1); stage B half 1 (B nq=1 reused)
        if (!last) STAGE_B(1);
        READ_A(0);
        BAR();
        CLUSTER(0, 1);
        if (!last) {
            // all 8 staged loads for tile t+1 must have landed before any
            // wave crosses into the next tile's ds_reads
            asm volatile("s_waitcnt vmcnt(0)" ::: "memory");
            __builtin_amdgcn_sched_barrier(0);
        }
        BAR();
    }

#undef STAGE_A
#undef STAGE_B
#undef READ_A
#undef READ_B
#undef CLUSTER
#undef BAR

    // epilogue: bias + SiLU + bf16 store
    // C/D layout: col = lane&15, row = quad*4 + reg   [verified m89]
    #pragma unroll
    for (int j = 0; j < 4; ++j) {
        const int col = n0 + wn * 64 + j * 16 + r16;
        const float bj = bias[col];
        #pragma unroll
        for (int i = 0; i < 8; ++i) {
            const int row_base = m0 + wm * 128 + i * 16 + quad * 4;
            #pragma unroll
            for (int rr = 0; rr < 4; ++rr) {
                const float v = acc[i][j][rr] + bj;
                const float s = v / (1.f + __expf(-v));
                C[(size_t)(row_base + rr) * H_DIM + col] = __float2bfloat16(s);
            }
        }
    }
}

// ---------------------------------------------------------------------------
// value[m] = sum_n H[m][n] * Wo[n] + bo      (N = 1024 fixed; 1 wave / row)
// ---------------------------------------------------------------------------
__global__ __launch_bounds__(256) void gemv_value_kernel(
    const __hip_bfloat16* __restrict__ H,
    const float* __restrict__ Wo,
    const float* __restrict__ bo_p,
    float* __restrict__ value, int M) {
    int wave = threadIdx.x >> 6, lane = threadIdx.x & 63;
    int row = blockIdx.x * 4 + wave;
    if (row >= M) return;
    const __hip_bfloat16* hrow = H + (size_t)row * H_DIM;
    float sum = 0.f;
    #pragma unroll
    for (int half = 0; half < 2; ++half) {
        int col = half * 512 + lane * 8;
        uint4 raw = *reinterpret_cast<const uint4*>(hrow + col);
        const __hip_bfloat16* hp = reinterpret_cast<const __hip_bfloat16*>(&raw);
        #pragma unroll
        for (int e = 0; e < 8; ++e)
            sum += __bfloat162float(hp[e]) * Wo[col + e];
    }
    #pragma unroll
    for (int off = 32; off > 0; off >>= 1)
        sum += __shfl_down(sum, off, 64);
    if (lane == 0) value[row] = sum + bo_p[0];
}

// ---------------------------------------------------------------------------
// GAE backward scan. value: (T,B) fp32. out: ret (63x512) then baseline.
// ---------------------------------------------------------------------------
__global__ __launch_bounds__(64) void gae_kernel(
    const float* __restrict__ value,
    const float* __restrict__ reward,
    const float* __restrict__ cont,
    float* __restrict__ out) {
    int b = blockIdx.x * blockDim.x + threadIdx.x;
    if (b >= B_DIM) return;
    float adv = 0.f;
    float v_next = value[(T_DIM - 1) * B_DIM + b];
    for (int t = T_DIM - 2; t >= 0; --t) {
        float v_t  = value[t * B_DIM + b];
        float disc = cont[(t + 1) * B_DIM + b] * DISCOUNT;
        float delta = reward[t * B_DIM + b] + disc * v_next - v_t;
        adv = delta + disc * LAM * adv;
        out[t * B_DIM + b] = adv + v_t;                           // ret
        out[(T_DIM - 1) * B_DIM + t * B_DIM + b] = v_t;           // baseline
        v_next = v_t;
    }
}

// ---------------------------------------------------------------------------
extern "C" void kernel_launch(void* const* d_in, const int* in_sizes, int n_in,
                              void* d_out, int out_size, void* d_ws, size_t ws_size,
                              hipStream_t stream) {
    const float* feat   = (const float*)d_in[0];
    const float* reward = (const float*)d_in[1];
    const float* cont   = (const float*)d_in[2];
    const float* W[4]   = {(const float*)d_in[3], (const float*)d_in[5],
                           (const float*)d_in[7], (const float*)d_in[9]};
    const float* bias[4] = {(const float*)d_in[4], (const float*)d_in[6],
                            (const float*)d_in[8], (const float*)d_in[10]};
    const float* Wo = (const float*)d_in[11];
    const float* bo = (const float*)d_in[12];
    float* out = (float*)d_out;

    // workspace layout
    char* ws = (char*)d_ws;
    __hip_bfloat16* Xb = (__hip_bfloat16*)ws; ws += (size_t)M_DIM * D_DIM * 2;   // 96 MB
    __hip_bfloat16* Ha = (__hip_bfloat16*)ws; ws += (size_t)M_DIM * H_DIM * 2;   // 64 MB
    __hip_bfloat16* Hb = (__hip_bfloat16*)ws; ws += (size_t)M_DIM * H_DIM * 2;   // 64 MB
    __hip_bfloat16* Wt0 = (__hip_bfloat16*)ws; ws += (size_t)H_DIM * D_DIM * 2;  // 3 MB
    __hip_bfloat16* Wt1 = (__hip_bfloat16*)ws; ws += (size_t)H_DIM * H_DIM * 2;
    __hip_bfloat16* Wt2 = (__hip_bfloat16*)ws; ws += (size_t)H_DIM * H_DIM * 2;
    __hip_bfloat16* Wt3 = (__hip_bfloat16*)ws; ws += (size_t)H_DIM * H_DIM * 2;
    float* value = (float*)ws; ws += (size_t)M_DIM * 4;

    // 1. feat -> bf16
    long n4 = (long)M_DIM * D_DIM / 4;
    cvt_bf16_kernel<<<(int)((n4 + 255) / 256), 256, 0, stream>>>(feat, Xb, n4);

    // 2. all weight transposes, one launch
    transpose_cvt_all_kernel<<<dim3(D_DIM / 32, H_DIM / 32, 4), dim3(32, 8), 0, stream>>>(
        W[0], W[1], W[2], W[3], Wt0, Wt1, Wt2, Wt3);

    // 3. MLP: 4 GEMM + SiLU layers (1D grid, XCD-swizzled inside)
    const int nblocks = TILES_M * TILES_N;  // 512
    gemm_silu_kernel<<<nblocks, 512, 0, stream>>>(Xb, Wt0, bias[0], Ha, D_DIM);
    gemm_silu_kernel<<<nblocks, 512, 0, stream>>>(Ha, Wt1, bias[1], Hb, H_DIM);
    gemm_silu_kernel<<<nblocks, 512, 0, stream>>>(Hb, Wt2, bias[2], Ha, H_DIM);
    gemm_silu_kernel<<<nblocks, 512, 0, stream>>>(Ha, Wt3, bias[3], Hb, H_DIM);

    // 4. value head GEMV
    gemv_value_kernel<<<M_DIM / 4, 256, 0, stream>>>(Hb, Wo, bo, value, M_DIM);

    // 5. GAE scan
    gae_kernel<<<8, 64, 0, stream>>>(value, reward, cont, out);
}